// Round 3
// baseline (355.781 us; speedup 1.0000x reference)
//
#include <hip/hip_runtime.h>

// Varlen depthwise conv (Canon layer): out = x + bias + sum_k mask*w[:,k]*x[t+k-2]
// T=65536 tokens, C=768 channels, K=5, NSEQ=16 packed sequences.
// Memory-bound: ~430 MB traffic -> ~70 us kernel roofline. Bench dur_us also
// includes ~248 us of harness poison fills (rocprof R1: top dispatches are all
// fillBufferAligned @124us; conv kernel < 124us).

#define CC  768          // channels
#define C4V (CC / 4)     // float4 chunks per row = 192 (block size, 3 waves)
#define KK  5            // kernel taps
#define RR  2            // radius
#define TPB 32           // tokens per block: (TPB+4)/TPB = 1.125x read amplification

// native clang vector (HIP float4 is a class; nontemporal builtin rejects it)
typedef float v4f __attribute__((ext_vector_type(4)));

__global__ __launch_bounds__(C4V) void canon_dwconv_kernel(
    const v4f* __restrict__ x4,
    const int* __restrict__ cu,     // cu_seqlens, nseq+1 entries, cu[nseq]=T
    int nseq,
    const float* __restrict__ weight, // [C, K] row-major
    const v4f* __restrict__ bias4,    // [C/4]
    v4f* __restrict__ out4,
    int T)
{
    const int c4 = threadIdx.x;
    const int t0 = (int)blockIdx.x * TPB;
    const int c  = c4 * 4;

    // Per-thread tap weights for 4 channels (15 KB table -> L1/L2-resident)
    float w[KK][4];
#pragma unroll
    for (int j = 0; j < 4; ++j)
#pragma unroll
        for (int k = 0; k < KK; ++k)
            w[k][j] = weight[(c + j) * KK + k];

    const v4f b = bias4[c4];

    // seq_id for t0 (searchsorted-right over cu[1:]); wave-uniform
    int sid = 0;
    while (sid < nseq && cu[sid + 1] <= t0) ++sid;
    const int start0 = cu[sid];
    const int end0   = cu[sid + 1];

    // Interior fast path: the whole halo [t0-2, t0+TPB+2) lies inside one
    // sequence -> all masks are 1, no cu loads in the loop, no clamps.
    // All blocks are interior except ~NSEQ boundary blocks and the two
    // array-edge blocks (start0>=0, end0<=T make edges non-interior).
    const bool interior = (start0 <= t0 - RR) && (end0 >= t0 + TPB + RR);

    v4f win[KK];

    if (interior) {
#pragma unroll
        for (int i = 0; i < KK - 1; ++i)
            win[i] = x4[(size_t)(t0 - RR + i) * C4V + c4];

#pragma unroll
        for (int tt = 0; tt < TPB; ++tt) {
            const int t = t0 + tt;
            win[(tt + KK - 1) % KK] = x4[(size_t)(t + RR) * C4V + c4];

            const v4f r0 = win[(tt + 0) % KK];
            const v4f r1 = win[(tt + 1) % KK];
            const v4f r2 = win[(tt + 2) % KK];
            const v4f r3 = win[(tt + 3) % KK];
            const v4f r4 = win[(tt + 4) % KK];

            v4f o;
#pragma unroll
            for (int j = 0; j < 4; ++j)
                o[j] = r2[j] + b[j] + r0[j] * w[0][j] + r1[j] * w[1][j]
                     + r2[j] * w[2][j] + r3[j] * w[3][j] + r4[j] * w[4][j];

            // write-only data: nontemporal, keep x rows in L2/L3 for reuse
            __builtin_nontemporal_store(o, &out4[(size_t)t * C4V + c4]);
        }
    } else {
        // Masked path: per-token seq bounds + boundary/edge masks
#pragma unroll
        for (int i = 0; i < KK - 1; ++i) {
            int r  = t0 - RR + i;
            int rc = min(max(r, 0), T - 1);
            win[i] = x4[(size_t)rc * C4V + c4];
        }

#pragma unroll
        for (int tt = 0; tt < TPB; ++tt) {
            const int t = t0 + tt;
            if (t < T) {
                int rc = min(t + RR, T - 1);
                win[(tt + KK - 1) % KK] = x4[(size_t)rc * C4V + c4];

                while (sid < nseq && cu[sid + 1] <= t) ++sid;
                const int start = cu[sid];
                const int end   = cu[sid + 1];

                const v4f r0 = win[(tt + 0) % KK];
                const v4f r1 = win[(tt + 1) % KK];
                const v4f r2 = win[(tt + 2) % KK];
                const v4f r3 = win[(tt + 3) % KK];
                const v4f r4 = win[(tt + 4) % KK];

                const float m0 = (t - 2 >= start) ? 1.0f : 0.0f;
                const float m1 = (t - 1 >= start) ? 1.0f : 0.0f;
                const float m3 = (t + 1 <  end)  ? 1.0f : 0.0f;
                const float m4 = (t + 2 <  end)  ? 1.0f : 0.0f;

                v4f o;
#pragma unroll
                for (int j = 0; j < 4; ++j)
                    o[j] = r2[j] + b[j] + r2[j] * w[2][j]
                         + r0[j] * (w[0][j] * m0) + r1[j] * (w[1][j] * m1)
                         + r3[j] * (w[3][j] * m3) + r4[j] * (w[4][j] * m4);

                __builtin_nontemporal_store(o, &out4[(size_t)t * C4V + c4]);
            }
        }
    }
}

extern "C" void kernel_launch(void* const* d_in, const int* in_sizes, int n_in,
                              void* d_out, int out_size, void* d_ws, size_t ws_size,
                              hipStream_t stream) {
    const v4f*   x4     = (const v4f*)d_in[0];
    const int*   cu     = (const int*)d_in[1];
    const float* weight = (const float*)d_in[2];
    const v4f*   bias4  = (const v4f*)d_in[3];
    v4f*         out4   = (v4f*)d_out;

    const int T    = in_sizes[0] / CC;
    const int nseq = in_sizes[1] - 1;

    const int grid = (T + TPB - 1) / TPB;
    canon_dwconv_kernel<<<grid, C4V, 0, stream>>>(x4, cu, nseq, weight, bias4, out4, T);
}